// Round 14
// baseline (274.101 us; speedup 1.0000x reference)
//
#include <hip/hip_runtime.h>
#include <hip/hip_bf16.h>

// DoubleConv: hypernet 3x3 radius-interp conv x2 + per-item BN+ReLU.
// Round 14: R12 structure (16x16x32, o-quarter waves, fma-D lerp) with hb-split
// As (130 rows, 33 KB) -> 3-4 blocks/CU occupancy for pipe overlap.

#define SD 6
#define HD 128
#define HYPER_OUT 294912
#define BN_EPS 1e-5f

typedef unsigned short ushort_t;
typedef __attribute__((ext_vector_type(8))) short bf16x8;
typedef __attribute__((ext_vector_type(4))) float f32x4;

__device__ inline ushort_t f2bf(float f) {
  union { float f; unsigned u; } v; v.f = f;
  unsigned r = v.u + 0x7fffu + ((v.u >> 16) & 1u);   // RNE
  return (ushort_t)(r >> 16);
}
__device__ inline float bf2f(ushort_t h) {
  union { unsigned u; float f; } v; v.u = ((unsigned)h) << 16; return v.f;
}
__device__ inline unsigned pack2(float a, float b) {
  return (unsigned)f2bf(a) | ((unsigned)f2bf(b) << 16);
}

// r = a + f*d, elementwise on bf16x8, compiler-scheduled cvt_pk
__device__ inline bf16x8 lerp8d(bf16x8 a, bf16x8 d, float f) {
  union U { bf16x8 v; unsigned u[4]; };
  U A, D, R;
  A.v = a; D.v = d;
  #pragma unroll
  for (int i = 0; i < 4; ++i) {
    float alo = __uint_as_float(A.u[i] << 16);
    float ahi = __uint_as_float(A.u[i] & 0xffff0000u);
    float dlo = __uint_as_float(D.u[i] << 16);
    float dhi = __uint_as_float(D.u[i] & 0xffff0000u);
    float rlo = fmaf(f, dlo, alo);
    float rhi = fmaf(f, dhi, ahi);
    __hip_bfloat162 h2 = __float22bfloat162_rn(float2{rlo, rhi});
    R.u[i] = *reinterpret_cast<unsigned*>(&h2);
  }
  return R.v;
}

// As element offset with XOR swizzle (16B-unit low-3 bits ^= row&7)
__device__ inline int as_off(int row, int cu) {    // As[130 rows][16 units of 8]
  return row*128 + ((cu ^ (row & 7)) << 3);
}

// ---------------- e-MLPs: e_all[16][128], row = item*8 + conv*4 + n ----------------
__global__ __launch_bounds__(128) void k_mlp(
    const float* __restrict__ seidel,
    const float* __restrict__ m1_w1, const float* __restrict__ m1_b1,
    const float* __restrict__ m1_w2, const float* __restrict__ m1_b2,
    const float* __restrict__ m2_w1, const float* __restrict__ m2_b1,
    const float* __restrict__ m2_w2, const float* __restrict__ m2_b2,
    float* __restrict__ e_all)
{
  int b = blockIdx.x;                 // 16 blocks
  int item = b >> 3, conv = (b >> 2) & 1, n = b & 3;
  const float* w1 = conv ? m2_w1 : m1_w1;
  const float* b1 = conv ? m2_b1 : m1_b1;
  const float* w2 = conv ? m2_w2 : m1_w2;
  const float* b2 = conv ? m2_b2 : m1_b2;
  int t = threadIdx.x;                // 128
  __shared__ float e1[HD];
  float s = b1[n*HD + t];
  #pragma unroll
  for (int i = 0; i < SD; ++i) s = fmaf(seidel[item*SD + i], w1[(n*SD + i)*HD + t], s);
  e1[t] = fmaxf(s, 0.f);
  __syncthreads();
  float s2 = b2[n*HD + t];
  for (int i = 0; i < HD; ++i) s2 = fmaf(e1[i], w2[(n*HD + i)*HD + t], s2);
  e_all[b*HD + t] = fmaxf(s2, 0.f);
}

// ---------------- hyper GEMM -> wb_lin[j][16] bf16 (coalesced writes) --------------
__global__ __launch_bounds__(256) void k_hyper(
    const float* __restrict__ e_all, const float* __restrict__ hyper_w,
    const float* __restrict__ hyper_b, ushort_t* __restrict__ wb_lin)
{
  __shared__ float es[16*HD];
  int t = threadIdx.x;
  for (int f = t; f < 16*HD; f += 256) es[f] = e_all[f];
  __syncthreads();
  int j = blockIdx.x*256 + t;         // 1152 * 256 = 294912
  float val[16];
  #pragma unroll
  for (int r = 0; r < 16; ++r) val[r] = 0.f;
  for (int i = 0; i < HD; ++i) {
    float hw = hyper_w[(size_t)i*HYPER_OUT + j];
    #pragma unroll
    for (int r = 0; r < 16; ++r) val[r] = fmaf(es[r*HD + i], hw, val[r]);
  }
  float bias = hyper_b[j];
  uint4 u0, u1;
  u0.x = pack2(val[0]+bias,  val[1]+bias);
  u0.y = pack2(val[2]+bias,  val[3]+bias);
  u0.z = pack2(val[4]+bias,  val[5]+bias);
  u0.w = pack2(val[6]+bias,  val[7]+bias);
  u1.x = pack2(val[8]+bias,  val[9]+bias);
  u1.y = pack2(val[10]+bias, val[11]+bias);
  u1.z = pack2(val[12]+bias, val[13]+bias);
  u1.w = pack2(val[14]+bias, val[15]+bias);
  *reinterpret_cast<uint4*>(wb_lin + (size_t)j*16)     = u0;
  *reinterpret_cast<uint4*>(wb_lin + (size_t)j*16 + 8) = u1;
}

// ---------------- fused prep: transpose x (blocks 0..4095) + repack (4096..5247) ----
// transpose: [item][c][h][w] f32 -> [item][w][h][c] bf16
// repack -> frag-linear W and D = W[nr+1]-W[nr] (D[7]=0):
//   wbW/wbD[(conv*2+item)][nr][kj][ki][ch(4 x c32)][oblk(8)][lane(64)][8 bf16]
__global__ __launch_bounds__(256) void k_prep(
    const float* __restrict__ x, ushort_t* __restrict__ xt,
    const ushort_t* __restrict__ wb_lin,
    ushort_t* __restrict__ wbW, ushort_t* __restrict__ wbD)
{
  __shared__ __align__(16) float tileF[64][65];     // transpose tile
  __shared__ ushort_t ldsN[16][256];                // repack: next-radius values
  int b = blockIdx.x;
  int t = threadIdx.x;
  if (b < 4096) {
    int wt = b & 3, ct = (b >> 2) & 1, z = b >> 3;
    int h = z & 255, item = z >> 8;
    {
      int cl = t >> 2, wk = (t & 3) << 4;
      const float* sp = x + (((size_t)item*128 + ct*64 + cl)*256 + h)*256 + wt*64 + wk;
      #pragma unroll
      for (int k = 0; k < 16; k += 4) {
        float4 v = *reinterpret_cast<const float4*>(sp + k);
        tileF[cl][wk+k] = v.x; tileF[cl][wk+k+1] = v.y;
        tileF[cl][wk+k+2] = v.z; tileF[cl][wk+k+3] = v.w;
      }
    }
    __syncthreads();
    {
      int wl = t >> 2, ck = (t & 3) << 4;
      ushort_t* dp = xt + (((size_t)item*256 + wt*64 + wl)*256 + h)*128 + ct*64 + ck;
      uint4 u0, u1;
      u0.x = pack2(tileF[ck+0][wl],  tileF[ck+1][wl]);
      u0.y = pack2(tileF[ck+2][wl],  tileF[ck+3][wl]);
      u0.z = pack2(tileF[ck+4][wl],  tileF[ck+5][wl]);
      u0.w = pack2(tileF[ck+6][wl],  tileF[ck+7][wl]);
      u1.x = pack2(tileF[ck+8][wl],  tileF[ck+9][wl]);
      u1.y = pack2(tileF[ck+10][wl], tileF[ck+11][wl]);
      u1.z = pack2(tileF[ck+12][wl], tileF[ck+13][wl]);
      u1.w = pack2(tileF[ck+14][wl], tileF[ck+15][wl]);
      *reinterpret_cast<uint4*>(dp)     = u0;
      *reinterpret_cast<uint4*>(dp + 8) = u1;
    }
  } else {
    int i = b - 4096;
    int chunk = i & 15;               // 0..15 (u-groups of 4)
    int tap   = i >> 4;               // 0..71
    int nr = tap / 9, kk = tap % 9;
    int ki = kk / 3, kj = kk % 3;
    int nrn = (nr < 7) ? nr + 1 : 7;
    ushort_t (*lds)[256] = reinterpret_cast<ushort_t(*)[256]>(tileF);
    int uv = chunk*256 + t;           // u = uv>>6, v = uv&63
    size_t j  = (size_t)uv*72 + nr*9 + kk;
    size_t j2 = (size_t)uv*72 + nrn*9 + kk;
    uint4 q0 = *reinterpret_cast<const uint4*>(wb_lin + j*16);
    uint4 q1 = *reinterpret_cast<const uint4*>(wb_lin + j*16 + 8);
    uint4 n0 = *reinterpret_cast<const uint4*>(wb_lin + j2*16);
    uint4 n1 = *reinterpret_cast<const uint4*>(wb_lin + j2*16 + 8);
    const ushort_t* pr0 = reinterpret_cast<const ushort_t*>(&q0);
    const ushort_t* pr1 = reinterpret_cast<const ushort_t*>(&q1);
    const ushort_t* pn0 = reinterpret_cast<const ushort_t*>(&n0);
    const ushort_t* pn1 = reinterpret_cast<const ushort_t*>(&n1);
    #pragma unroll
    for (int r = 0; r < 8; ++r) { lds[r][t]  = pr0[r]; ldsN[r][t]  = pn0[r]; }
    #pragma unroll
    for (int r = 0; r < 8; ++r) { lds[r+8][t] = pr1[r]; ldsN[r+8][t] = pn1[r]; }
    __syncthreads();
    #pragma unroll
    for (int it = 0; it < 2; ++it) {
      int idx = it*256 + t;           // 512 row-segments (8 consecutive c at fixed o)
      int row = idx >> 3, seg = idx & 7;
      int p = row >> 2, ul = row & 3;
      int item = p >> 3, conv = (p >> 2) & 1, n = p & 3;
      int o  = (n >> 1)*64 + chunk*4 + ul;
      int c8 = (n & 1)*8 + seg;        // c/8
      int ch = c8 >> 2, gq = c8 & 3;
      int oblk = o >> 4, ol = o & 15;
      uint4 v = *reinterpret_cast<const uint4*>(&lds[p][ul*64 + seg*8]);
      uint4 d4;
      {
        const ushort_t* pw = reinterpret_cast<const ushort_t*>(&v);
        const ushort_t* pnx = &ldsN[p][ul*64 + seg*8];
        ushort_t* pd = reinterpret_cast<ushort_t*>(&d4);
        #pragma unroll
        for (int e = 0; e < 8; ++e) pd[e] = f2bf(bf2f(pnx[e]) - bf2f(pw[e]));
      }
      size_t off = (size_t)(conv*2 + item)*1179648
                 + ((((size_t)nr*3 + kj)*3 + ki)*4 + ch)*4096
                 + oblk*512 + (gq*16 + ol)*8;
      *reinterpret_cast<uint4*>(wbW + off) = v;
      *reinterpret_cast<uint4*>(wbD + off) = d4;
    }
  }
}

// ---------------- MFMA conv: hb-split, 4 o-quarter waves, fma-D lerp ---------------
// src [item][w][h][c] bf16 ; wbW/wbD frag-linear
// dst [item][w][h][o] bf16 pre-BN ; ps/p2 partials [1024][128]
// grid 1024 (XCD-swizzled), 256 threads = 4 waves, each 32 o x 128 h.
template<bool BN_IN>
__global__ __launch_bounds__(256, 3) void k_conv(
    const ushort_t* __restrict__ src,
    const ushort_t* __restrict__ wbW, const ushort_t* __restrict__ wbD,
    const float* __restrict__ bn_a, const float* __restrict__ bn_c,
    ushort_t* __restrict__ dst, float* __restrict__ ps, float* __restrict__ p2)
{
  __shared__ __align__(16) ushort_t As[130*128];    // 33,280 B (swizzled)
  __shared__ float sbn[256];
  int bid = blockIdx.x;
  int wgid = ((bid & 7) << 7) | (bid >> 3);          // XCD-contiguous, hb adjacent
  int item = wgid >> 9;
  int w    = (wgid >> 1) & 255;
  int hb   = wgid & 1;
  int t = threadIdx.x;
  int lane = t & 63, wid = t >> 6;
  int l15 = lane & 15, g = lane >> 4;

  float pos = fminf(fmaxf((w + 0.5f)*0.03125f - 0.5f, 0.f), 7.f);
  int i0 = (int)pos; float fr = pos - (float)i0;

  if constexpr (BN_IN) {
    sbn[t] = (t < 128) ? bn_a[item*128 + t] : bn_c[item*128 + (t - 128)];
    __syncthreads();                                 // sbn visible before stage_as
  }

  // per-lane weight fragment base (wave owns oblk = wid*2 + mf, mf=0..1)
  const ushort_t* wpW = wbW + (size_t)item*1179648 + (size_t)i0*147456
                      + (wid*2)*512 + lane*8;
  const ushort_t* wpD = wbD + (size_t)item*1179648 + (size_t)i0*147456
                      + (wid*2)*512 + lane*8;

  f32x4 acc[2][8];
  #pragma unroll
  for (int a = 0; a < 2; ++a)
    #pragma unroll
    for (int b = 0; b < 8; ++b)
      acc[a][b] = (f32x4){0.f, 0.f, 0.f, 0.f};

  // stage As (130 halo rows) for a given kj
  auto stage_as = [&](int kj) {
    int wc = w + kj - 1;
    bool valid = (wc >= 0) && (wc < 256);
    const ushort_t* sb = src + ((size_t)item*256 + (valid ? wc : 0))*32768;
    for (int f = t; f < 130*16; f += 256) {
      int row = f >> 4, cu = f & 15;
      uint4 v = make_uint4(0u, 0u, 0u, 0u);
      if (valid) {
        int hg = (hb*128 + row - 1) & 255;           // circular pad in H
        v = *reinterpret_cast<const uint4*>(sb + ((size_t)hg << 7) + (cu << 3));
        if constexpr (BN_IN) {
          ushort_t* pv = reinterpret_cast<ushort_t*>(&v);
          int c0 = cu << 3;
          #pragma unroll
          for (int jj = 0; jj < 8; ++jj) {
            float xv = bf2f(pv[jj]);
            xv = fmaxf(fmaf(sbn[c0 + jj], xv, sbn[128 + c0 + jj]), 0.f);
            pv[jj] = f2bf(xv);
          }
        }
      }
      *reinterpret_cast<uint4*>(&As[as_off(row, cu)]) = v;
    }
  };

  auto loadraw = [&](bf16x8* rw, bf16x8* rd, int s) {
    size_t so = (size_t)s*4096;
    #pragma unroll
    for (int mf = 0; mf < 2; ++mf) {
      rw[mf] = *reinterpret_cast<const bf16x8*>(wpW + so + mf*512);
      rd[mf] = *reinterpret_cast<const bf16x8*>(wpD + so + mf*512);
    }
  };

  bf16x8 rwA[2], rdA[2], rwB[2], rdB[2], lw[2];
  loadraw(rwA, rdA, 0);                              // prologue

  for (int kj = 0; kj < 3; ++kj) {
    __syncthreads();                                 // prev kj's readers done
    stage_as(kj);
    __syncthreads();                                 // As visible
    #pragma unroll
    for (int s2 = 0; s2 < 12; ++s2) {                // s2 = ki*4 + ch
      int ki = s2 >> 2, ch = s2 & 3;
      int s = kj*12 + s2;
      bf16x8* cw = (s2 & 1) ? rwB : rwA;
      bf16x8* cd = (s2 & 1) ? rdB : rdA;
      bf16x8* nw = (s2 & 1) ? rwA : rwB;
      bf16x8* nd = (s2 & 1) ? rdA : rdB;
      loadraw(nw, nd, (s + 1 < 36) ? (s + 1) : 35);  // prefetch next raw pair
      #pragma unroll
      for (int mf = 0; mf < 2; ++mf) lw[mf] = lerp8d(cw[mf], cd[mf], fr);
      #pragma unroll
      for (int pass = 0; pass < 2; ++pass) {
        bf16x8 bfr[4];
        #pragma unroll
        for (int q = 0; q < 4; ++q) {
          int nf = pass*4 + q;
          bfr[q] = *reinterpret_cast<const bf16x8*>(
              &As[as_off(nf*16 + l15 + ki, (ch << 2) + g)]);
        }
        #pragma unroll
        for (int mf = 0; mf < 2; ++mf)
          #pragma unroll
          for (int q = 0; q < 4; ++q)
            acc[mf][pass*4 + q] = __builtin_amdgcn_mfma_f32_16x16x32_bf16(
                lw[mf], bfr[q], acc[mf][pass*4 + q], 0, 0, 0);
      }
    }
  }

  // epilogue: store bf16 [h][o], BN partials
  ushort_t* yb = dst + (((size_t)item*256 + w)*256 + hb*128)*128;
  float ssum[2][4], s2sum[2][4];
  #pragma unroll
  for (int a = 0; a < 2; ++a)
    #pragma unroll
    for (int b = 0; b < 4; ++b) { ssum[a][b] = 0.f; s2sum[a][b] = 0.f; }
  #pragma unroll
  for (int mf = 0; mf < 2; ++mf) {
    #pragma unroll
    for (int nf = 0; nf < 8; ++nf) {
      float v[4];
      #pragma unroll
      for (int r4 = 0; r4 < 4; ++r4) {
        v[r4] = acc[mf][nf][r4];
        ssum[mf][r4] += v[r4];
        s2sum[mf][r4] = fmaf(v[r4], v[r4], s2sum[mf][r4]);
      }
      int h  = nf*16 + l15;
      int o0 = wid*32 + mf*16 + (g << 2);
      uint2 u; u.x = pack2(v[0], v[1]); u.y = pack2(v[2], v[3]);
      *reinterpret_cast<uint2*>(yb + (size_t)h*128 + o0) = u;
    }
  }
  #pragma unroll
  for (int mf = 0; mf < 2; ++mf)
    #pragma unroll
    for (int r4 = 0; r4 < 4; ++r4)
      #pragma unroll
      for (int m = 1; m < 16; m <<= 1) {
        ssum[mf][r4]  += __shfl_xor(ssum[mf][r4], m);
        s2sum[mf][r4] += __shfl_xor(s2sum[mf][r4], m);
      }
  __syncthreads();                                   // reuse As as scratch
  float* redS  = reinterpret_cast<float*>(As);       // [128] o-linear
  float* redS2 = redS + 128;
  if (l15 == 0) {
    #pragma unroll
    for (int mf = 0; mf < 2; ++mf)
      #pragma unroll
      for (int r4 = 0; r4 < 4; ++r4) {
        int o = wid*32 + mf*16 + (g << 2) + r4;      // each o owned by ONE wave
        redS [o] = ssum[mf][r4];
        redS2[o] = s2sum[mf][r4];
      }
  }
  __syncthreads();
  if (t < 128) {
    size_t bi = ((size_t)item*256 + w)*2 + hb;
    ps[bi*128 + t] = redS[t];
    p2[bi*128 + t] = redS2[t];
  }
}

// ---------------- reduce partials -> BN affine: 256 blocks (item x channel) --------
__global__ __launch_bounds__(256) void k_bnapply(
    const float* __restrict__ ps, const float* __restrict__ p2,
    const float* __restrict__ gamma, const float* __restrict__ beta,
    float* __restrict__ bn_a, float* __restrict__ bn_c)
{
  int item = blockIdx.x >> 7, o = blockIdx.x & 127;
  int t = threadIdx.x;
  size_t b0 = (size_t)(item*512 + t)*128 + o;
  size_t b1 = (size_t)(item*512 + 256 + t)*128 + o;
  float s  = ps[b0] + ps[b1];
  float s2 = p2[b0] + p2[b1];
  #pragma unroll
  for (int m = 1; m < 64; m <<= 1) { s += __shfl_xor(s, m); s2 += __shfl_xor(s2, m); }
  __shared__ float rs[4], rs2[4];
  if ((t & 63) == 0) { rs[t >> 6] = s; rs2[t >> 6] = s2; }
  __syncthreads();
  if (t == 0) {
    s  = rs[0] + rs[1] + rs[2] + rs[3];
    s2 = rs2[0] + rs2[1] + rs2[2] + rs2[3];
    float mu  = s  * (1.f/65536.f);
    float var = s2 * (1.f/65536.f) - mu*mu;
    float a = gamma[o] * rsqrtf(var + BN_EPS);
    bn_a[item*128 + o] = a;
    bn_c[item*128 + o] = beta[o] - a*mu;
  }
}

// ---------------- final: BN2+ReLU + transpose [item][w][h][o] bf16 -> NCHW f32 ------
__global__ __launch_bounds__(256) void k_final(
    const ushort_t* __restrict__ y, const float* __restrict__ bn_a,
    const float* __restrict__ bn_c, float* __restrict__ out)
{
  __shared__ float tile[64][65];      // [w][o]
  int wt = blockIdx.x, ot = blockIdx.y;
  int h = blockIdx.z & 255, item = blockIdx.z >> 8;
  int t = threadIdx.x;
  {
    int wl = t >> 2, ck = (t & 3) << 4;
    const ushort_t* sp = y + (((size_t)item*256 + wt*64 + wl)*256 + h)*128 + ot*64 + ck;
    uint4 a = *reinterpret_cast<const uint4*>(sp);
    uint4 b = *reinterpret_cast<const uint4*>(sp + 8);
    const ushort_t* pa = reinterpret_cast<const ushort_t*>(&a);
    const ushort_t* pb = reinterpret_cast<const ushort_t*>(&b);
    #pragma unroll
    for (int k = 0; k < 8; ++k) {
      int o = ot*64 + ck + k;
      tile[wl][ck + k] = fmaxf(fmaf(bn_a[item*128 + o], bf2f(pa[k]), bn_c[item*128 + o]), 0.f);
    }
    #pragma unroll
    for (int k = 0; k < 8; ++k) {
      int o = ot*64 + ck + 8 + k;
      tile[wl][ck + 8 + k] = fmaxf(fmaf(bn_a[item*128 + o], bf2f(pb[k]), bn_c[item*128 + o]), 0.f);
    }
  }
  __syncthreads();
  {
    int ol = t >> 2, wk = (t & 3) << 4;
    float* dp = out + (((size_t)item*128 + ot*64 + ol)*256 + h)*256 + wt*64 + wk;
    #pragma unroll
    for (int k = 0; k < 16; k += 4) {
      float4 v;
      v.x = tile[wk+k][ol];   v.y = tile[wk+k+1][ol];
      v.z = tile[wk+k+2][ol]; v.w = tile[wk+k+3][ol];
      *reinterpret_cast<float4*>(dp + k) = v;
    }
  }
}

extern "C" void kernel_launch(void* const* d_in, const int* in_sizes, int n_in,
                              void* d_out, int out_size, void* d_ws, size_t ws_size,
                              hipStream_t stream) {
  const float* x       = (const float*)d_in[0];
  const float* seidel  = (const float*)d_in[1];
  const float* m1_w1   = (const float*)d_in[2];
  const float* m1_b1   = (const float*)d_in[3];
  const float* m1_w2   = (const float*)d_in[4];
  const float* m1_b2   = (const float*)d_in[5];
  const float* m2_w1   = (const float*)d_in[6];
  const float* m2_b1   = (const float*)d_in[7];
  const float* m2_w2   = (const float*)d_in[8];
  const float* m2_b2   = (const float*)d_in[9];
  const float* hyper_w = (const float*)d_in[10];
  const float* hyper_b = (const float*)d_in[11];
  const float* bn1_g   = (const float*)d_in[12];
  const float* bn1_b   = (const float*)d_in[13];
  const float* bn2_g   = (const float*)d_in[14];
  const float* bn2_b   = (const float*)d_in[15];

  char* ws = (char*)d_ws;
  float*    e_all  = (float*)ws;                                    // 8,192
  ushort_t* wb_lin = (ushort_t*)(ws + 8192);                        // 9,437,184
  ushort_t* wbW    = (ushort_t*)(ws + 9445376);                     // 9,437,184
  ushort_t* wbD    = (ushort_t*)(ws + 18882560);                    // 9,437,184
  ushort_t* xt     = (ushort_t*)(ws + 28319744);                    // 33,554,432
  ushort_t* y1     = (ushort_t*)(ws + 61874176);                    // 33,554,432
  ushort_t* y2     = (ushort_t*)(ws + 95428608);                    // 33,554,432
  float*    ps     = (float*)(ws + 128983040);                      // 524,288
  float*    p2     = (float*)(ws + 129507328);                      // 524,288
  float*    bnb    = (float*)(ws + 130031616);                      // 4 KB
  float* bn1_a = bnb,        *bn1_c = bnb + 256;
  float* bn2_a = bnb + 512,  *bn2_c = bnb + 768;

  k_mlp<<<16, 128, 0, stream>>>(seidel, m1_w1, m1_b1, m1_w2, m1_b2,
                                m2_w1, m2_b1, m2_w2, m2_b2, e_all);
  k_hyper<<<HYPER_OUT/256, 256, 0, stream>>>(e_all, hyper_w, hyper_b, wb_lin);
  k_prep<<<5248, 256, 0, stream>>>(x, xt, wb_lin, wbW, wbD);

  k_conv<false><<<1024, 256, 0, stream>>>(xt, wbW, wbD, nullptr, nullptr, y1, ps, p2);
  k_bnapply<<<256, 256, 0, stream>>>(ps, p2, bn1_g, bn1_b, bn1_a, bn1_c);

  k_conv<true><<<1024, 256, 0, stream>>>(y1, wbW + 2359296, wbD + 2359296,
                                         bn1_a, bn1_c, y2, ps, p2);
  k_bnapply<<<256, 256, 0, stream>>>(ps, p2, bn2_g, bn2_b, bn2_a, bn2_c);
  k_final<<<dim3(4, 2, 512), 256, 0, stream>>>(y2, bn2_a, bn2_c, (float*)d_out);
}

// Round 15
// 256.602 us; speedup vs baseline: 1.0682x; 1.0682x over previous
//
#include <hip/hip_runtime.h>
#include <hip/hip_bf16.h>

// DoubleConv: hypernet 3x3 radius-interp conv x2 + per-item BN+ReLU.
// Round 15: revert to the round-12 optimum (257 us): full-column blocks,
// 16x16x32 MFMA, 4 o-quarter waves, single-radius fma-D register lerp,
// frag-linear weights, 256-block BN reduce.

#define SD 6
#define HD 128
#define HYPER_OUT 294912
#define BN_EPS 1e-5f

typedef unsigned short ushort_t;
typedef __attribute__((ext_vector_type(8))) short bf16x8;
typedef __attribute__((ext_vector_type(4))) float f32x4;

__device__ inline ushort_t f2bf(float f) {
  union { float f; unsigned u; } v; v.f = f;
  unsigned r = v.u + 0x7fffu + ((v.u >> 16) & 1u);   // RNE
  return (ushort_t)(r >> 16);
}
__device__ inline float bf2f(ushort_t h) {
  union { unsigned u; float f; } v; v.u = ((unsigned)h) << 16; return v.f;
}
__device__ inline unsigned pack2(float a, float b) {
  return (unsigned)f2bf(a) | ((unsigned)f2bf(b) << 16);
}

// r = a + f*d, elementwise on bf16x8, compiler-scheduled cvt_pk
__device__ inline bf16x8 lerp8d(bf16x8 a, bf16x8 d, float f) {
  union U { bf16x8 v; unsigned u[4]; };
  U A, D, R;
  A.v = a; D.v = d;
  #pragma unroll
  for (int i = 0; i < 4; ++i) {
    float alo = __uint_as_float(A.u[i] << 16);
    float ahi = __uint_as_float(A.u[i] & 0xffff0000u);
    float dlo = __uint_as_float(D.u[i] << 16);
    float dhi = __uint_as_float(D.u[i] & 0xffff0000u);
    float rlo = fmaf(f, dlo, alo);
    float rhi = fmaf(f, dhi, ahi);
    __hip_bfloat162 h2 = __float22bfloat162_rn(float2{rlo, rhi});
    R.u[i] = *reinterpret_cast<unsigned*>(&h2);
  }
  return R.v;
}

// As element offset with XOR swizzle (16B-unit low-3 bits ^= row&7)
__device__ inline int as_off(int row, int cu) {    // As[258 rows][16 units of 8]
  return row*128 + ((cu ^ (row & 7)) << 3);
}

// ---------------- e-MLPs: e_all[16][128], row = item*8 + conv*4 + n ----------------
__global__ __launch_bounds__(128) void k_mlp(
    const float* __restrict__ seidel,
    const float* __restrict__ m1_w1, const float* __restrict__ m1_b1,
    const float* __restrict__ m1_w2, const float* __restrict__ m1_b2,
    const float* __restrict__ m2_w1, const float* __restrict__ m2_b1,
    const float* __restrict__ m2_w2, const float* __restrict__ m2_b2,
    float* __restrict__ e_all)
{
  int b = blockIdx.x;                 // 16 blocks
  int item = b >> 3, conv = (b >> 2) & 1, n = b & 3;
  const float* w1 = conv ? m2_w1 : m1_w1;
  const float* b1 = conv ? m2_b1 : m1_b1;
  const float* w2 = conv ? m2_w2 : m1_w2;
  const float* b2 = conv ? m2_b2 : m1_b2;
  int t = threadIdx.x;                // 128
  __shared__ float e1[HD];
  float s = b1[n*HD + t];
  #pragma unroll
  for (int i = 0; i < SD; ++i) s = fmaf(seidel[item*SD + i], w1[(n*SD + i)*HD + t], s);
  e1[t] = fmaxf(s, 0.f);
  __syncthreads();
  float s2 = b2[n*HD + t];
  for (int i = 0; i < HD; ++i) s2 = fmaf(e1[i], w2[(n*HD + i)*HD + t], s2);
  e_all[b*HD + t] = fmaxf(s2, 0.f);
}

// ---------------- hyper GEMM -> wb_lin[j][16] bf16 (coalesced writes) --------------
__global__ __launch_bounds__(256) void k_hyper(
    const float* __restrict__ e_all, const float* __restrict__ hyper_w,
    const float* __restrict__ hyper_b, ushort_t* __restrict__ wb_lin)
{
  __shared__ float es[16*HD];
  int t = threadIdx.x;
  for (int f = t; f < 16*HD; f += 256) es[f] = e_all[f];
  __syncthreads();
  int j = blockIdx.x*256 + t;         // 1152 * 256 = 294912
  float val[16];
  #pragma unroll
  for (int r = 0; r < 16; ++r) val[r] = 0.f;
  for (int i = 0; i < HD; ++i) {
    float hw = hyper_w[(size_t)i*HYPER_OUT + j];
    #pragma unroll
    for (int r = 0; r < 16; ++r) val[r] = fmaf(es[r*HD + i], hw, val[r]);
  }
  float bias = hyper_b[j];
  uint4 u0, u1;
  u0.x = pack2(val[0]+bias,  val[1]+bias);
  u0.y = pack2(val[2]+bias,  val[3]+bias);
  u0.z = pack2(val[4]+bias,  val[5]+bias);
  u0.w = pack2(val[6]+bias,  val[7]+bias);
  u1.x = pack2(val[8]+bias,  val[9]+bias);
  u1.y = pack2(val[10]+bias, val[11]+bias);
  u1.z = pack2(val[12]+bias, val[13]+bias);
  u1.w = pack2(val[14]+bias, val[15]+bias);
  *reinterpret_cast<uint4*>(wb_lin + (size_t)j*16)     = u0;
  *reinterpret_cast<uint4*>(wb_lin + (size_t)j*16 + 8) = u1;
}

// ---------------- fused prep: transpose x (blocks 0..4095) + repack (4096..5247) ----
// transpose: [item][c][h][w] f32 -> [item][w][h][c] bf16
// repack -> frag-linear W and D = W[nr+1]-W[nr] (D[7]=0):
//   wbW/wbD[(conv*2+item)][nr][kj][ki][ch(4 x c32)][oblk(8)][lane(64)][8 bf16]
__global__ __launch_bounds__(256) void k_prep(
    const float* __restrict__ x, ushort_t* __restrict__ xt,
    const ushort_t* __restrict__ wb_lin,
    ushort_t* __restrict__ wbW, ushort_t* __restrict__ wbD)
{
  __shared__ __align__(16) float tileF[64][65];     // transpose tile
  __shared__ ushort_t ldsN[16][256];                // repack: next-radius values
  int b = blockIdx.x;
  int t = threadIdx.x;
  if (b < 4096) {
    int wt = b & 3, ct = (b >> 2) & 1, z = b >> 3;
    int h = z & 255, item = z >> 8;
    {
      int cl = t >> 2, wk = (t & 3) << 4;
      const float* sp = x + (((size_t)item*128 + ct*64 + cl)*256 + h)*256 + wt*64 + wk;
      #pragma unroll
      for (int k = 0; k < 16; k += 4) {
        float4 v = *reinterpret_cast<const float4*>(sp + k);
        tileF[cl][wk+k] = v.x; tileF[cl][wk+k+1] = v.y;
        tileF[cl][wk+k+2] = v.z; tileF[cl][wk+k+3] = v.w;
      }
    }
    __syncthreads();
    {
      int wl = t >> 2, ck = (t & 3) << 4;
      ushort_t* dp = xt + (((size_t)item*256 + wt*64 + wl)*256 + h)*128 + ct*64 + ck;
      uint4 u0, u1;
      u0.x = pack2(tileF[ck+0][wl],  tileF[ck+1][wl]);
      u0.y = pack2(tileF[ck+2][wl],  tileF[ck+3][wl]);
      u0.z = pack2(tileF[ck+4][wl],  tileF[ck+5][wl]);
      u0.w = pack2(tileF[ck+6][wl],  tileF[ck+7][wl]);
      u1.x = pack2(tileF[ck+8][wl],  tileF[ck+9][wl]);
      u1.y = pack2(tileF[ck+10][wl], tileF[ck+11][wl]);
      u1.z = pack2(tileF[ck+12][wl], tileF[ck+13][wl]);
      u1.w = pack2(tileF[ck+14][wl], tileF[ck+15][wl]);
      *reinterpret_cast<uint4*>(dp)     = u0;
      *reinterpret_cast<uint4*>(dp + 8) = u1;
    }
  } else {
    int i = b - 4096;
    int chunk = i & 15;               // 0..15 (u-groups of 4)
    int tap   = i >> 4;               // 0..71
    int nr = tap / 9, kk = tap % 9;
    int ki = kk / 3, kj = kk % 3;
    int nrn = (nr < 7) ? nr + 1 : 7;
    ushort_t (*lds)[256] = reinterpret_cast<ushort_t(*)[256]>(tileF);
    int uv = chunk*256 + t;           // u = uv>>6, v = uv&63
    size_t j  = (size_t)uv*72 + nr*9 + kk;
    size_t j2 = (size_t)uv*72 + nrn*9 + kk;
    uint4 q0 = *reinterpret_cast<const uint4*>(wb_lin + j*16);
    uint4 q1 = *reinterpret_cast<const uint4*>(wb_lin + j*16 + 8);
    uint4 n0 = *reinterpret_cast<const uint4*>(wb_lin + j2*16);
    uint4 n1 = *reinterpret_cast<const uint4*>(wb_lin + j2*16 + 8);
    const ushort_t* pr0 = reinterpret_cast<const ushort_t*>(&q0);
    const ushort_t* pr1 = reinterpret_cast<const ushort_t*>(&q1);
    const ushort_t* pn0 = reinterpret_cast<const ushort_t*>(&n0);
    const ushort_t* pn1 = reinterpret_cast<const ushort_t*>(&n1);
    #pragma unroll
    for (int r = 0; r < 8; ++r) { lds[r][t]  = pr0[r]; ldsN[r][t]  = pn0[r]; }
    #pragma unroll
    for (int r = 0; r < 8; ++r) { lds[r+8][t] = pr1[r]; ldsN[r+8][t] = pn1[r]; }
    __syncthreads();
    #pragma unroll
    for (int it = 0; it < 2; ++it) {
      int idx = it*256 + t;           // 512 row-segments (8 consecutive c at fixed o)
      int row = idx >> 3, seg = idx & 7;
      int p = row >> 2, ul = row & 3;
      int item = p >> 3, conv = (p >> 2) & 1, n = p & 3;
      int o  = (n >> 1)*64 + chunk*4 + ul;
      int c8 = (n & 1)*8 + seg;        // c/8
      int ch = c8 >> 2, gq = c8 & 3;
      int oblk = o >> 4, ol = o & 15;
      uint4 v = *reinterpret_cast<const uint4*>(&lds[p][ul*64 + seg*8]);
      uint4 d4;
      {
        const ushort_t* pw = reinterpret_cast<const ushort_t*>(&v);
        const ushort_t* pnx = &ldsN[p][ul*64 + seg*8];
        ushort_t* pd = reinterpret_cast<ushort_t*>(&d4);
        #pragma unroll
        for (int e = 0; e < 8; ++e) pd[e] = f2bf(bf2f(pnx[e]) - bf2f(pw[e]));
      }
      size_t off = (size_t)(conv*2 + item)*1179648
                 + ((((size_t)nr*3 + kj)*3 + ki)*4 + ch)*4096
                 + oblk*512 + (gq*16 + ol)*8;
      *reinterpret_cast<uint4*>(wbW + off) = v;
      *reinterpret_cast<uint4*>(wbD + off) = d4;
    }
  }
}

// ---------------- MFMA conv: full-column block, 4 o-quarter waves ------------------
// src [item][w][h][c] bf16 ; wbW/wbD frag-linear
// dst [item][w][h][o] bf16 pre-BN ; ps/p2 partials [512][128]
// grid 512 (XCD-swizzled), 256 threads = 4 waves, each 32 o x 256 h.
template<bool BN_IN>
__global__ __launch_bounds__(256, 2) void k_conv(
    const ushort_t* __restrict__ src,
    const ushort_t* __restrict__ wbW, const ushort_t* __restrict__ wbD,
    const float* __restrict__ bn_a, const float* __restrict__ bn_c,
    ushort_t* __restrict__ dst, float* __restrict__ ps, float* __restrict__ p2)
{
  __shared__ __align__(16) ushort_t As[258*128];    // 66,048 B (swizzled)
  __shared__ float sbn[256];
  int bid = blockIdx.x;
  int wgid = ((bid & 7) << 6) | (bid >> 3);          // XCD-contiguous, 512 blocks
  int item = wgid >> 8;
  int w    = wgid & 255;
  int t = threadIdx.x;
  int lane = t & 63, wid = t >> 6;
  int l15 = lane & 15, g = lane >> 4;

  float pos = fminf(fmaxf((w + 0.5f)*0.03125f - 0.5f, 0.f), 7.f);
  int i0 = (int)pos; float fr = pos - (float)i0;

  if constexpr (BN_IN) {
    sbn[t] = (t < 128) ? bn_a[item*128 + t] : bn_c[item*128 + (t - 128)];
    __syncthreads();                                 // sbn visible before stage_as
  }

  // per-lane weight fragment base (wave owns oblk = wid*2 + mf, mf=0..1)
  const ushort_t* wpW = wbW + (size_t)item*1179648 + (size_t)i0*147456
                      + (wid*2)*512 + lane*8;
  const ushort_t* wpD = wbD + (size_t)item*1179648 + (size_t)i0*147456
                      + (wid*2)*512 + lane*8;

  f32x4 acc[2][16];
  #pragma unroll
  for (int a = 0; a < 2; ++a)
    #pragma unroll
    for (int b = 0; b < 16; ++b)
      acc[a][b] = (f32x4){0.f, 0.f, 0.f, 0.f};

  // stage As (258 halo rows, full column) for a given kj
  auto stage_as = [&](int kj) {
    int wc = w + kj - 1;
    bool valid = (wc >= 0) && (wc < 256);
    const ushort_t* sb = src + ((size_t)item*256 + (valid ? wc : 0))*32768;
    for (int f = t; f < 258*16; f += 256) {
      int row = f >> 4, cu = f & 15;
      uint4 v = make_uint4(0u, 0u, 0u, 0u);
      if (valid) {
        int hg = (row + 255) & 255;                  // circular pad in H
        v = *reinterpret_cast<const uint4*>(sb + ((size_t)hg << 7) + (cu << 3));
        if constexpr (BN_IN) {
          ushort_t* pv = reinterpret_cast<ushort_t*>(&v);
          int c0 = cu << 3;
          #pragma unroll
          for (int jj = 0; jj < 8; ++jj) {
            float xv = bf2f(pv[jj]);
            xv = fmaxf(fmaf(sbn[c0 + jj], xv, sbn[128 + c0 + jj]), 0.f);
            pv[jj] = f2bf(xv);
          }
        }
      }
      *reinterpret_cast<uint4*>(&As[as_off(row, cu)]) = v;
    }
  };

  auto loadraw = [&](bf16x8* rw, bf16x8* rd, int s) {
    size_t so = (size_t)s*4096;
    #pragma unroll
    for (int mf = 0; mf < 2; ++mf) {
      rw[mf] = *reinterpret_cast<const bf16x8*>(wpW + so + mf*512);
      rd[mf] = *reinterpret_cast<const bf16x8*>(wpD + so + mf*512);
    }
  };

  bf16x8 rwA[2], rdA[2], rwB[2], rdB[2], lw[2];
  loadraw(rwA, rdA, 0);                              // prologue

  for (int kj = 0; kj < 3; ++kj) {
    __syncthreads();                                 // prev kj's readers done
    stage_as(kj);
    __syncthreads();                                 // As visible
    #pragma unroll
    for (int s2 = 0; s2 < 12; ++s2) {                // s2 = ki*4 + ch
      int ki = s2 >> 2, ch = s2 & 3;
      int s = kj*12 + s2;
      bf16x8* cw = (s2 & 1) ? rwB : rwA;
      bf16x8* cd = (s2 & 1) ? rdB : rdA;
      bf16x8* nw = (s2 & 1) ? rwA : rwB;
      bf16x8* nd = (s2 & 1) ? rdA : rdB;
      loadraw(nw, nd, (s + 1 < 36) ? (s + 1) : 35);  // prefetch next raw pair
      #pragma unroll
      for (int mf = 0; mf < 2; ++mf) lw[mf] = lerp8d(cw[mf], cd[mf], fr);
      #pragma unroll
      for (int pass = 0; pass < 4; ++pass) {
        bf16x8 bfr[4];
        #pragma unroll
        for (int q = 0; q < 4; ++q) {
          int nf = pass*4 + q;
          bfr[q] = *reinterpret_cast<const bf16x8*>(
              &As[as_off(nf*16 + l15 + ki, (ch << 2) + g)]);
        }
        #pragma unroll
        for (int mf = 0; mf < 2; ++mf)
          #pragma unroll
          for (int q = 0; q < 4; ++q)
            acc[mf][pass*4 + q] = __builtin_amdgcn_mfma_f32_16x16x32_bf16(
                lw[mf], bfr[q], acc[mf][pass*4 + q], 0, 0, 0);
      }
    }
  }

  // epilogue: store bf16 [h][o], BN partials
  ushort_t* yb = dst + ((size_t)item*256 + w)*32768;
  float ssum[2][4], s2sum[2][4];
  #pragma unroll
  for (int a = 0; a < 2; ++a)
    #pragma unroll
    for (int b = 0; b < 4; ++b) { ssum[a][b] = 0.f; s2sum[a][b] = 0.f; }
  #pragma unroll
  for (int mf = 0; mf < 2; ++mf) {
    #pragma unroll
    for (int nf = 0; nf < 16; ++nf) {
      float v[4];
      #pragma unroll
      for (int r4 = 0; r4 < 4; ++r4) {
        v[r4] = acc[mf][nf][r4];
        ssum[mf][r4] += v[r4];
        s2sum[mf][r4] = fmaf(v[r4], v[r4], s2sum[mf][r4]);
      }
      int h  = nf*16 + l15;
      int o0 = wid*32 + mf*16 + (g << 2);
      uint2 u; u.x = pack2(v[0], v[1]); u.y = pack2(v[2], v[3]);
      *reinterpret_cast<uint2*>(yb + (size_t)h*128 + o0) = u;
    }
  }
  #pragma unroll
  for (int mf = 0; mf < 2; ++mf)
    #pragma unroll
    for (int r4 = 0; r4 < 4; ++r4)
      #pragma unroll
      for (int m = 1; m < 16; m <<= 1) {
        ssum[mf][r4]  += __shfl_xor(ssum[mf][r4], m);
        s2sum[mf][r4] += __shfl_xor(s2sum[mf][r4], m);
      }
  __syncthreads();                                   // reuse As as scratch
  float* redS  = reinterpret_cast<float*>(As);       // [128] o-linear
  float* redS2 = redS + 128;
  if (l15 == 0) {
    #pragma unroll
    for (int mf = 0; mf < 2; ++mf)
      #pragma unroll
      for (int r4 = 0; r4 < 4; ++r4) {
        int o = wid*32 + mf*16 + (g << 2) + r4;      // each o owned by ONE wave
        redS [o] = ssum[mf][r4];
        redS2[o] = s2sum[mf][r4];
      }
  }
  __syncthreads();
  if (t < 128) {
    size_t bi = (size_t)item*256 + w;
    ps[bi*128 + t] = redS[t];
    p2[bi*128 + t] = redS2[t];
  }
}

// ---------------- reduce partials -> BN affine: 256 blocks (item x channel) --------
__global__ __launch_bounds__(256) void k_bnapply(
    const float* __restrict__ ps, const float* __restrict__ p2,
    const float* __restrict__ gamma, const float* __restrict__ beta,
    float* __restrict__ bn_a, float* __restrict__ bn_c)
{
  int item = blockIdx.x >> 7, o = blockIdx.x & 127;
  int t = threadIdx.x;
  size_t bi = (size_t)(item*256 + t)*128 + o;
  float s  = ps[bi];
  float s2 = p2[bi];
  #pragma unroll
  for (int m = 1; m < 64; m <<= 1) { s += __shfl_xor(s, m); s2 += __shfl_xor(s2, m); }
  __shared__ float rs[4], rs2[4];
  if ((t & 63) == 0) { rs[t >> 6] = s; rs2[t >> 6] = s2; }
  __syncthreads();
  if (t == 0) {
    s  = rs[0] + rs[1] + rs[2] + rs[3];
    s2 = rs2[0] + rs2[1] + rs2[2] + rs2[3];
    float mu  = s  * (1.f/65536.f);
    float var = s2 * (1.f/65536.f) - mu*mu;
    float a = gamma[o] * rsqrtf(var + BN_EPS);
    bn_a[item*128 + o] = a;
    bn_c[item*128 + o] = beta[o] - a*mu;
  }
}

// ---------------- final: BN2+ReLU + transpose [item][w][h][o] bf16 -> NCHW f32 ------
__global__ __launch_bounds__(256) void k_final(
    const ushort_t* __restrict__ y, const float* __restrict__ bn_a,
    const float* __restrict__ bn_c, float* __restrict__ out)
{
  __shared__ float tile[64][65];      // [w][o]
  int wt = blockIdx.x, ot = blockIdx.y;
  int h = blockIdx.z & 255, item = blockIdx.z >> 8;
  int t = threadIdx.x;
  {
    int wl = t >> 2, ck = (t & 3) << 4;
    const ushort_t* sp = y + (((size_t)item*256 + wt*64 + wl)*256 + h)*128 + ot*64 + ck;
    uint4 a = *reinterpret_cast<const uint4*>(sp);
    uint4 b = *reinterpret_cast<const uint4*>(sp + 8);
    const ushort_t* pa = reinterpret_cast<const ushort_t*>(&a);
    const ushort_t* pb = reinterpret_cast<const ushort_t*>(&b);
    #pragma unroll
    for (int k = 0; k < 8; ++k) {
      int o = ot*64 + ck + k;
      tile[wl][ck + k] = fmaxf(fmaf(bn_a[item*128 + o], bf2f(pa[k]), bn_c[item*128 + o]), 0.f);
    }
    #pragma unroll
    for (int k = 0; k < 8; ++k) {
      int o = ot*64 + ck + 8 + k;
      tile[wl][ck + 8 + k] = fmaxf(fmaf(bn_a[item*128 + o], bf2f(pb[k]), bn_c[item*128 + o]), 0.f);
    }
  }
  __syncthreads();
  {
    int ol = t >> 2, wk = (t & 3) << 4;
    float* dp = out + (((size_t)item*128 + ot*64 + ol)*256 + h)*256 + wt*64 + wk;
    #pragma unroll
    for (int k = 0; k < 16; k += 4) {
      float4 v;
      v.x = tile[wk+k][ol];   v.y = tile[wk+k+1][ol];
      v.z = tile[wk+k+2][ol]; v.w = tile[wk+k+3][ol];
      *reinterpret_cast<float4*>(dp + k) = v;
    }
  }
}

extern "C" void kernel_launch(void* const* d_in, const int* in_sizes, int n_in,
                              void* d_out, int out_size, void* d_ws, size_t ws_size,
                              hipStream_t stream) {
  const float* x       = (const float*)d_in[0];
  const float* seidel  = (const float*)d_in[1];
  const float* m1_w1   = (const float*)d_in[2];
  const float* m1_b1   = (const float*)d_in[3];
  const float* m1_w2   = (const float*)d_in[4];
  const float* m1_b2   = (const float*)d_in[5];
  const float* m2_w1   = (const float*)d_in[6];
  const float* m2_b1   = (const float*)d_in[7];
  const float* m2_w2   = (const float*)d_in[8];
  const float* m2_b2   = (const float*)d_in[9];
  const float* hyper_w = (const float*)d_in[10];
  const float* hyper_b = (const float*)d_in[11];
  const float* bn1_g   = (const float*)d_in[12];
  const float* bn1_b   = (const float*)d_in[13];
  const float* bn2_g   = (const float*)d_in[14];
  const float* bn2_b   = (const float*)d_in[15];

  char* ws = (char*)d_ws;
  float*    e_all  = (float*)ws;                                    // 8,192
  ushort_t* wb_lin = (ushort_t*)(ws + 8192);                        // 9,437,184
  ushort_t* wbW    = (ushort_t*)(ws + 9445376);                     // 9,437,184
  ushort_t* wbD    = (ushort_t*)(ws + 18882560);                    // 9,437,184
  ushort_t* xt     = (ushort_t*)(ws + 28319744);                    // 33,554,432
  ushort_t* y1     = (ushort_t*)(ws + 61874176);                    // 33,554,432
  ushort_t* y2     = (ushort_t*)(ws + 95428608);                    // 33,554,432
  float*    ps     = (float*)(ws + 128983040);                      // 262,144
  float*    p2     = (float*)(ws + 129245184);                      // 262,144
  float*    bnb    = (float*)(ws + 129507328);                      // 4 KB
  float* bn1_a = bnb,        *bn1_c = bnb + 256;
  float* bn2_a = bnb + 512,  *bn2_c = bnb + 768;

  k_mlp<<<16, 128, 0, stream>>>(seidel, m1_w1, m1_b1, m1_w2, m1_b2,
                                m2_w1, m2_b1, m2_w2, m2_b2, e_all);
  k_hyper<<<HYPER_OUT/256, 256, 0, stream>>>(e_all, hyper_w, hyper_b, wb_lin);
  k_prep<<<5248, 256, 0, stream>>>(x, xt, wb_lin, wbW, wbD);

  k_conv<false><<<512, 256, 0, stream>>>(xt, wbW, wbD, nullptr, nullptr, y1, ps, p2);
  k_bnapply<<<256, 256, 0, stream>>>(ps, p2, bn1_g, bn1_b, bn1_a, bn1_c);

  k_conv<true><<<512, 256, 0, stream>>>(y1, wbW + 2359296, wbD + 2359296,
                                        bn1_a, bn1_c, y2, ps, p2);
  k_bnapply<<<256, 256, 0, stream>>>(ps, p2, bn2_g, bn2_b, bn2_a, bn2_c);
  k_final<<<dim3(4, 2, 512), 256, 0, stream>>>(y2, bn2_a, bn2_c, (float*)d_out);
}